// Round 13
// baseline (59.276 us; speedup 1.0000x reference)
//
#include <hip/hip_runtime.h>
#include <math.h>

#define NN 4096
#define BB 8
#define NV4 (NN / 4)        // float4 per row = 1024
#define CF4 128             // float4 per K-chunk (512 floats), 2 sub-passes
#define NCHUNK (NV4 / CF4)  // 8
#define ROWS 16             // rows per block -> grid 256 = 1 block/CU
#define RPW 4               // rows per wave (R6-identical wave work)

// R6 champion structure scaled: 1024 thr = 16 waves = 4 gates x 4 row-groups,
// every wave identical to R6's (4 full rows, acc[4][8], matrix reg rotation,
// 2 sub-passes per chunk). ONE vbuf serves 16 waves -> per-block x/h global
// reads amortized over 2x rows: global-path bytes 399->335 MB.
// R0-R11 post-mortem: limiter is per-CU global-load-path rate (~11.6
// B/cyc/CU in R6, >= m13 copy bench); only total path bytes remain.
__global__ __launch_bounds__(1024, 1) void attgru_fused_kernel(
    const float* __restrict__ x,   const float* __restrict__ h,
    const float* __restrict__ adj, const float* __restrict__ Whr,
    const float* __restrict__ bhr, const float* __restrict__ Whz,
    const float* __restrict__ bhz, const float* __restrict__ Whn,
    const float* __restrict__ bhn, float* __restrict__ out)
{
    const int t    = threadIdx.x;
    const int lane = t & 63;
    const int wave = t >> 6;      // 0..15
    const int gate = wave & 3;    // 0:agg 1:r 2:z 3:n
    const int rgrp = wave >> 2;   // 0..3 row-group
    const int row0 = blockIdx.x * ROWS;

    __shared__ float4 vbuf[2][2][BB][CF4];  // [buf][x/h][batch][pos] 64 KB
    __shared__ float  red[16][RPW * BB];    // per-wave complete sums, 2 KB

    const float* Msel = (gate == 0) ? adj : (gate == 1) ? Whr
                      : (gate == 2) ? Whz : Whn;
    const int vsel = (gate != 0);
    const float4* M4 = reinterpret_cast<const float4*>(Msel)
                     + (size_t)(row0 + rgrp * RPW) * NV4;
    const float4* x4 = reinterpret_cast<const float4*>(x);
    const float4* h4 = reinterpret_cast<const float4*>(h);

    // Staging: thread t stages batch (t>>7), pos (t&127), one float4 of x
    // AND one of h per chunk (1024 threads cover all 2048 slots).
    const int sb = t >> 7, sl = t & 127;
    const float4* srcx = x4 + sb * NV4;
    const float4* srch = h4 + sb * NV4;

    // ---- prologue: stage chunk 0, load matrix sub0 of chunk 0 ----
    float4 mc[RPW];
#pragma unroll
    for (int r = 0; r < RPW; ++r) mc[r] = M4[r * NV4 + lane];
    vbuf[0][0][sb][sl] = srcx[sl];
    vbuf[0][1][sb][sl] = srch[sl];
    __syncthreads();

    float acc[RPW][BB];
#pragma unroll
    for (int r = 0; r < RPW; ++r)
#pragma unroll
        for (int b = 0; b < BB; ++b) acc[r][b] = 0.f;

    for (int c = 0; c < NCHUNK; ++c) {
        const int cur = c & 1, nxt = cur ^ 1;
        const bool more = (c + 1 < NCHUNK);

        // issue next-chunk vector loads early
        float4 rx, rh;
        if (more) {
            const int vc = (c + 1) * CF4 + sl;
            rx = srcx[vc];
            rh = srch[vc];
        }
        // matrix regs for sub1 of this chunk
        float4 mn[RPW];
#pragma unroll
        for (int r = 0; r < RPW; ++r)
            mn[r] = M4[r * NV4 + c * CF4 + 64 + lane];

        // ---- sub-pass 0: positions [0,64) ----
#pragma unroll
        for (int b = 0; b < BB; ++b) {
            const float4 vb = vbuf[cur][vsel][b][lane];
#pragma unroll
            for (int r = 0; r < RPW; ++r)
                acc[r][b] += mc[r].x * vb.x + mc[r].y * vb.y
                           + mc[r].z * vb.z + mc[r].w * vb.w;
        }

        // prefetch matrix sub0 of next chunk
        float4 mc2[RPW];
        if (more) {
#pragma unroll
            for (int r = 0; r < RPW; ++r)
                mc2[r] = M4[r * NV4 + (c + 1) * CF4 + lane];
        }

        // ---- sub-pass 1: positions [64,128) ----
#pragma unroll
        for (int b = 0; b < BB; ++b) {
            const float4 vb = vbuf[cur][vsel][b][64 + lane];
#pragma unroll
            for (int r = 0; r < RPW; ++r)
                acc[r][b] += mn[r].x * vb.x + mn[r].y * vb.y
                           + mn[r].z * vb.z + mn[r].w * vb.w;
        }

        if (more) {
            vbuf[nxt][0][sb][sl] = rx;
            vbuf[nxt][1][sb][sl] = rh;
#pragma unroll
            for (int r = 0; r < RPW; ++r) mc[r] = mc2[r];
            __syncthreads();
        }
    }

    // full-wave butterfly: all lanes end with the wave's complete sums
#pragma unroll
    for (int off = 32; off >= 1; off >>= 1)
#pragma unroll
        for (int r = 0; r < RPW; ++r)
#pragma unroll
            for (int b = 0; b < BB; ++b)
                acc[r][b] += __shfl_xor(acc[r][b], off);

    if (lane == 0) {
#pragma unroll
        for (int r = 0; r < RPW; ++r)
#pragma unroll
            for (int b = 0; b < BB; ++b)
                red[wave][r * BB + b] = acc[r][b];
    }
    __syncthreads();

    if (t < ROWS * BB) {   // 128 outputs per block
        const int r = t >> 3, b = t & 7;
        const int rg2 = r >> 2, rr = r & 3;       // wave = rg2*4 + gate
        const int row = row0 + r;
        const float agg = red[rg2 * 4 + 0][rr * BB + b];
        const float rs  = red[rg2 * 4 + 1][rr * BB + b];
        const float zs  = red[rg2 * 4 + 2][rr * BB + b];
        const float ns  = red[rg2 * 4 + 3][rr * BB + b];
        const float rgt = 1.f / (1.f + __expf(-(agg + rs + bhr[row])));
        const float zgt = 1.f / (1.f + __expf(-(agg + zs + bhz[row])));
        const float ngt = tanhf(agg + rgt * (ns + bhn[row]));
        const float hv  = h[b * NN + row];
        out[b * NN + row] = (1.f - zgt) * ngt + zgt * hv;
    }
}

extern "C" void kernel_launch(void* const* d_in, const int* in_sizes, int n_in,
                              void* d_out, int out_size, void* d_ws, size_t ws_size,
                              hipStream_t stream) {
    const float* x   = (const float*)d_in[0];
    const float* h   = (const float*)d_in[1];
    const float* adj = (const float*)d_in[2];
    const float* Whr = (const float*)d_in[3];
    const float* bhr = (const float*)d_in[4];
    const float* Whz = (const float*)d_in[5];
    const float* bhz = (const float*)d_in[6];
    const float* Whn = (const float*)d_in[7];
    const float* bhn = (const float*)d_in[8];
    float* out = (float*)d_out;

    const int grid = NN / ROWS;   // 256 blocks x 16 waves, 1 block/CU
    attgru_fused_kernel<<<grid, 1024, 0, stream>>>(x, h, adj, Whr, bhr, Whz,
                                                   bhz, Whn, bhn, out);
}